// Round 4
// baseline (521.434 us; speedup 1.0000x reference)
//
#include <hip/hip_runtime.h>

// ---------------------------------------------------------------------------
// GCN forward (R16: permuted feature layout + destination time-phased fill):
//   A16/H16 store feature f = t*16+m at position m*8+t (pi). GEMM epilogue is
//   then ONE half8 store per output row fragment (was 32 x 2B scattered).
//   Consumers are elementwise; W2/W3 fragments take K-row sigma(k) =
//   (k&7)*16 + (k>>3); b1/b2/b3/lin_w get permuted copies (prep).
//   fill: 8 edges/thread in regs, 4 destination quarter-window phases so a
//   node's bucket lines receive all writes within one phase (write-combine).
//   prep:   [wcast | bias-permute | count_deg(8/thread)] one launch
//   build:  scan1(+dinv) -> scan2 -> scan3 -> [gemm1 | fill] merged
//   layer2: H16 @ W2 -> A16' ; agg -> H16   (A16' prescaled by dinv[row])
//   layer3: H16 @ W3 -> A16' ; head agg + lin_w dot -> nodeval -> segreduce
// ---------------------------------------------------------------------------

typedef __attribute__((ext_vector_type(4))) float f32x4;
typedef __attribute__((ext_vector_type(8))) _Float16 half8;

// ---- device helpers -------------------------------------------------------

__device__ __forceinline__ void gemm_f32_body(const float* __restrict__ H,
                                              const _Float16* __restrict__ W16,
                                              const float* __restrict__ dinv,
                                              _Float16* __restrict__ T16,
                                              int N, int bid) {
    const int tid = threadIdx.x;
    const int wv = tid >> 6;
    const int lane = tid & 63;
    const int r0 = bid * 64 + wv * 16;
    const int mrow = lane & 15;
    const int kq = lane >> 4;
    const int grow = r0 + mrow;
    const bool rok = grow < N;

    f32x4 acc[8];
    #pragma unroll
    for (int t = 0; t < 8; ++t) acc[t] = (f32x4){0.f, 0.f, 0.f, 0.f};

    #pragma unroll
    for (int c = 0; c < 4; ++c) {
        half8 a = (half8)(_Float16)0;
        if (rok) {
            const f32x4* Hp = (const f32x4*)(H + (size_t)grow * 128 + c * 32 + kq * 8);
            f32x4 a0 = __builtin_nontemporal_load(Hp);
            f32x4 a1 = __builtin_nontemporal_load(Hp + 1);
            a[0] = (_Float16)a0[0]; a[1] = (_Float16)a0[1];
            a[2] = (_Float16)a0[2]; a[3] = (_Float16)a0[3];
            a[4] = (_Float16)a1[0]; a[5] = (_Float16)a1[1];
            a[6] = (_Float16)a1[2]; a[7] = (_Float16)a1[3];
        }
        #pragma unroll
        for (int t = 0; t < 8; ++t) {
            half8 w = *(const half8*)&W16[(((c * 8 + t) * 64) + lane) * 8];
            acc[t] = __builtin_amdgcn_mfma_f32_16x16x32_f16(a, w, acc[t], 0, 0, 0);
        }
    }
    // permuted store: feature t*16+mrow -> position mrow*8+t (contiguous half8)
    #pragma unroll
    for (int r = 0; r < 4; ++r) {
        int orow = r0 + kq * 4 + r;
        if (orow < N) {
            float dv = dinv[orow];
            half8 o;
            #pragma unroll
            for (int t = 0; t < 8; ++t) o[t] = (_Float16)(acc[t][r] * dv);
            *(half8*)(T16 + (size_t)orow * 128 + mrow * 8) = o;
        }
    }
}

// ---- merged launch 1: wcast (192) | bias-permute (192..199) | count_deg ---
// wcast: W[128][128] fp32 -> fp16 MFMA B-fragments. Layers 2/3 use K-row
// sigma(k) = (k&7)*16 + (k>>3) to match the permuted H16 storage order.
__global__ __launch_bounds__(256) void prep_kernel(const float* __restrict__ W1,
                                                   const float* __restrict__ W2,
                                                   const float* __restrict__ W3,
                                                   const float* __restrict__ b1,
                                                   const float* __restrict__ b2,
                                                   const float* __restrict__ b3,
                                                   const float* __restrict__ lin_w,
                                                   _Float16* __restrict__ W16,
                                                   float* __restrict__ bperm,
                                                   const int* __restrict__ col,
                                                   int* __restrict__ deg,
                                                   int E, int partSize) {
    if (blockIdx.x < 192) {
        int layer = blockIdx.x >> 6;
        const float* W = (layer == 0) ? W1 : (layer == 1) ? W2 : W3;
        _Float16* Wd = W16 + layer * 16384;
        int i = (blockIdx.x & 63) * 256 + threadIdx.x;
        int j = i & 7;
        int l = (i >> 3) & 63;
        int t = (i >> 9) & 7;
        int c = i >> 12;
        int k = c * 32 + (l >> 4) * 8 + j;
        int ksrc = (layer == 0) ? k : ((k & 7) * 16 + (k >> 3));
        int n = t * 16 + (l & 15);
        Wd[i] = (_Float16)W[ksrc * 128 + n];
    } else if (blockIdx.x < 200) {
        int a = blockIdx.x - 192;
        if (a < 4 && threadIdx.x < 128) {
            const float* src = (a == 0) ? b1 : (a == 1) ? b2 : (a == 2) ? b3 : lin_w;
            int p2 = threadIdx.x;
            bperm[a * 128 + p2] = src[(p2 & 7) * 16 + (p2 >> 3)];
        }
    } else {
        int bid = blockIdx.x - 200;           // 200 % 8 == 0: p<->XCD mapping kept
        const int p = bid & 7;
        const int lo = p * partSize;
        const int e0 = (bid >> 3) * 2048 + threadIdx.x * 8;
        if (e0 >= E) return;
        if (((E & 3) == 0) && e0 + 7 < E) {
            int4 cA = *(const int4*)&col[e0];
            int4 cB = *(const int4*)&col[e0 + 4];
            if ((unsigned)(cA.x - lo) < (unsigned)partSize) atomicAdd(&deg[cA.x], 1);
            if ((unsigned)(cA.y - lo) < (unsigned)partSize) atomicAdd(&deg[cA.y], 1);
            if ((unsigned)(cA.z - lo) < (unsigned)partSize) atomicAdd(&deg[cA.z], 1);
            if ((unsigned)(cA.w - lo) < (unsigned)partSize) atomicAdd(&deg[cA.w], 1);
            if ((unsigned)(cB.x - lo) < (unsigned)partSize) atomicAdd(&deg[cB.x], 1);
            if ((unsigned)(cB.y - lo) < (unsigned)partSize) atomicAdd(&deg[cB.y], 1);
            if ((unsigned)(cB.z - lo) < (unsigned)partSize) atomicAdd(&deg[cB.z], 1);
            if ((unsigned)(cB.w - lo) < (unsigned)partSize) atomicAdd(&deg[cB.w], 1);
        } else {
            for (int j2 = 0; j2 < 8; ++j2) {
                int e = e0 + j2;
                if (e < E) {
                    int c = col[e];
                    if ((unsigned)(c - lo) < (unsigned)partSize) atomicAdd(&deg[c], 1);
                }
            }
        }
    }
}

// per-block exclusive scan of deg (1024/block) -> rowptr; also dinv = rsqrt(deg+1)
__global__ __launch_bounds__(256) void scan1_kernel(const int* __restrict__ deg,
                                                    int* __restrict__ rowptr,
                                                    float* __restrict__ dinv,
                                                    int* __restrict__ blockSums, int N) {
    __shared__ int ts[256];
    const int t = threadIdx.x;
    const int base = blockIdx.x * 1024 + t * 4;
    int v0 = 0, v1 = 0, v2 = 0, v3 = 0;
    if (base + 3 < N) {
        int4 v = *(const int4*)&deg[base];
        v0 = v.x; v1 = v.y; v2 = v.z; v3 = v.w;
    } else {
        if (base + 0 < N) v0 = deg[base + 0];
        if (base + 1 < N) v1 = deg[base + 1];
        if (base + 2 < N) v2 = deg[base + 2];
        if (base + 3 < N) v3 = deg[base + 3];
    }
    if (base + 0 < N) dinv[base + 0] = 1.0f / sqrtf((float)v0 + 1.0f);
    if (base + 1 < N) dinv[base + 1] = 1.0f / sqrtf((float)v1 + 1.0f);
    if (base + 2 < N) dinv[base + 2] = 1.0f / sqrtf((float)v2 + 1.0f);
    if (base + 3 < N) dinv[base + 3] = 1.0f / sqrtf((float)v3 + 1.0f);
    const int tot = v0 + v1 + v2 + v3;
    ts[t] = tot;
    __syncthreads();
    for (int off = 1; off < 256; off <<= 1) {
        int add = (t >= off) ? ts[t - off] : 0;
        __syncthreads();
        ts[t] += add;
        __syncthreads();
    }
    const int excl = ts[t] - tot;
    if (base + 0 < N) rowptr[base + 0] = excl;
    if (base + 1 < N) rowptr[base + 1] = excl + v0;
    if (base + 2 < N) rowptr[base + 2] = excl + v0 + v1;
    if (base + 3 < N) rowptr[base + 3] = excl + v0 + v1 + v2;
    if (t == 255) blockSums[blockIdx.x] = ts[255];
}

__global__ __launch_bounds__(128) void scan2_kernel(const int* __restrict__ blockSums,
                                                    int* __restrict__ blockOffs, int B) {
    __shared__ int ts[128];
    const int t = threadIdx.x;
    ts[t] = (t < B) ? blockSums[t] : 0;
    __syncthreads();
    for (int off = 1; off < 128; off <<= 1) {
        int add = (t >= off) ? ts[t - off] : 0;
        __syncthreads();
        ts[t] += add;
        __syncthreads();
    }
    if (t < B) blockOffs[t] = ts[t];
}

__global__ __launch_bounds__(256) void scan3_kernel(int* __restrict__ rowptr,
                                                    const int* __restrict__ blockOffs, int N) {
    int i = blockIdx.x * 256 + threadIdx.x;
    if (i >= N) return;
    int b = i >> 10;
    if (b > 0) rowptr[i] += blockOffs[b - 1];
}

// ---- merged launch 2: gemm1 (gBlocks) | fill (rest) -----------------------
// fill: 8 edges/thread in regs; 4 destination quarter-window phases so all
// writes to a bucket line land close in time (L2 write-combining survives
// the co-scheduled gemm1 stream). Exact boundaries -> each edge once.
__global__ __launch_bounds__(256) void fill_gemm1_kernel(
        const float* __restrict__ x, const _Float16* __restrict__ W16,
        const float* __restrict__ dinv, _Float16* __restrict__ A16,
        int N, int gBlocks, const int* __restrict__ ei,
        int* __restrict__ rowptr, int* __restrict__ edges, int E, int partSize) {
    if ((int)blockIdx.x < gBlocks) {
        gemm_f32_body(x, W16, dinv, A16, N, blockIdx.x);
    } else {
        int bid = blockIdx.x - gBlocks;
        const int p = bid & 7;                // consistent p<->XCD shift (bijection)
        const int lo = p * partSize;
        const int e0 = (bid >> 3) * 2048 + threadIdx.x * 8;
        if (e0 >= E) return;
        if (((E & 3) == 0) && e0 + 7 < E) {
            int4 cA = *(const int4*)&ei[E + e0];
            int4 cB = *(const int4*)&ei[E + e0 + 4];
            int4 rA = *(const int4*)&ei[e0];
            int4 rB = *(const int4*)&ei[e0 + 4];
            #pragma unroll
            for (int ph = 0; ph < 4; ++ph) {
                const int w0 = lo + ((ph * partSize) >> 2);
                const unsigned wl = (unsigned)((((ph + 1) * partSize) >> 2)
                                             - ((ph * partSize) >> 2));
                if ((unsigned)(cA.x - w0) < wl) edges[atomicAdd(&rowptr[cA.x], 1)] = rA.x;
                if ((unsigned)(cA.y - w0) < wl) edges[atomicAdd(&rowptr[cA.y], 1)] = rA.y;
                if ((unsigned)(cA.z - w0) < wl) edges[atomicAdd(&rowptr[cA.z], 1)] = rA.z;
                if ((unsigned)(cA.w - w0) < wl) edges[atomicAdd(&rowptr[cA.w], 1)] = rA.w;
                if ((unsigned)(cB.x - w0) < wl) edges[atomicAdd(&rowptr[cB.x], 1)] = rB.x;
                if ((unsigned)(cB.y - w0) < wl) edges[atomicAdd(&rowptr[cB.y], 1)] = rB.y;
                if ((unsigned)(cB.z - w0) < wl) edges[atomicAdd(&rowptr[cB.z], 1)] = rB.z;
                if ((unsigned)(cB.w - w0) < wl) edges[atomicAdd(&rowptr[cB.w], 1)] = rB.w;
            }
        } else {
            for (int j = 0; j < 8; ++j) {
                int e = e0 + j;
                if (e < E) {
                    int c = ei[E + e];
                    if ((unsigned)(c - lo) < (unsigned)partSize) {
                        int pos = atomicAdd(&rowptr[c], 1);
                        edges[pos] = ei[e];
                    }
                }
            }
        }
    }
}

// A16' = fp16( dinv[row] * (H16 @ W16) ), permuted store (layers 2/3)
__global__ __launch_bounds__(256) void gemm_f16_kernel(const _Float16* __restrict__ H16,
                                                       const _Float16* __restrict__ W16,
                                                       const float* __restrict__ dinv,
                                                       _Float16* __restrict__ T16,
                                                       int N) {
    const int tid = threadIdx.x;
    const int wv = tid >> 6;
    const int lane = tid & 63;
    const int r0 = blockIdx.x * 64 + wv * 16;
    const int mrow = lane & 15;
    const int kq = lane >> 4;
    const int grow = r0 + mrow;
    const bool rok = grow < N;

    f32x4 acc[8];
    #pragma unroll
    for (int t = 0; t < 8; ++t) acc[t] = (f32x4){0.f, 0.f, 0.f, 0.f};

    #pragma unroll
    for (int c = 0; c < 4; ++c) {
        half8 a = (half8)(_Float16)0;
        if (rok) a = *(const half8*)(H16 + (size_t)grow * 128 + c * 32 + kq * 8);
        #pragma unroll
        for (int t = 0; t < 8; ++t) {
            half8 w = *(const half8*)&W16[(((c * 8 + t) * 64) + lane) * 8];
            acc[t] = __builtin_amdgcn_mfma_f32_16x16x32_f16(a, w, acc[t], 0, 0, 0);
        }
    }
    #pragma unroll
    for (int r = 0; r < 4; ++r) {
        int orow = r0 + kq * 4 + r;
        if (orow < N) {
            float dv = dinv[orow];
            half8 o;
            #pragma unroll
            for (int t = 0; t < 8; ++t) o[t] = (_Float16)(acc[t][r] * dv);
            *(half8*)(T16 + (size_t)orow * 128 + mrow * 8) = o;
        }
    }
}

// one wave per node; 8 lanes/edge; lane covers chunks (q, 8+q) => each load
// instruction reads a contiguous 128B (2 full lines) of the source row.
// All feature data (A16, H16, bias', lin_w') is in permuted order; the agg is
// elementwise so the code is order-agnostic.
__global__ __launch_bounds__(256) void agg_kernel(const int* __restrict__ rowptr,
                                                  const int* __restrict__ edges,
                                                  const float* __restrict__ dinv,
                                                  const _Float16* __restrict__ A16,
                                                  const float* __restrict__ bias,
                                                  _Float16* __restrict__ H16, int N) {
    int w = (blockIdx.x * 256 + threadIdx.x) >> 6;
    if (w >= N) return;
    const int lane = threadIdx.x & 63;
    const int g = lane >> 3;
    const int q = lane & 7;
    const int beg = (w > 0) ? rowptr[w - 1] : 0;
    const int end = rowptr[w];
    const float dn = dinv[w];
    const half8* A8 = (const half8*)A16;

    int myid = (beg + lane < end) ? edges[beg + lane] : 0;
    half8 sA = (half8)(_Float16)0, sB = (half8)(_Float16)0;
    if (g == 0) {
        sA = A8[(size_t)w * 16 + q];
        sB = A8[(size_t)w * 16 + 8 + q];
    }

    float4 a0 = make_float4(0.f, 0.f, 0.f, 0.f);
    float4 a1 = make_float4(0.f, 0.f, 0.f, 0.f);
    float4 a2 = make_float4(0.f, 0.f, 0.f, 0.f);
    float4 a3 = make_float4(0.f, 0.f, 0.f, 0.f);
    for (int base = beg; base < end; base += 16) {
        const int r0 = base - beg + g;
        const int r1 = r0 + 8;
        const int e0 = base + g;
        const int e1 = e0 + 8;
        const bool v0 = e0 < end;
        const bool v1 = e1 < end;
        int s0 = __shfl(myid, r0 < 64 ? r0 : 63);
        int s1 = __shfl(myid, r1 < 64 ? r1 : 63);
        if (r0 >= 64 && v0) s0 = edges[e0];
        if (r1 >= 64 && v1) s1 = edges[e1];
        half8 h00, h01, h10, h11;
        if (v0) {
            const half8* R = A8 + (size_t)s0 * 16 + q;
            h00 = R[0]; h01 = R[8];
        }
        if (v1) {
            const half8* R = A8 + (size_t)s1 * 16 + q;
            h10 = R[0]; h11 = R[8];
        }
        if (v0) {
            a0.x += (float)h00[0]; a0.y += (float)h00[1];
            a0.z += (float)h00[2]; a0.w += (float)h00[3];
            a1.x += (float)h00[4]; a1.y += (float)h00[5];
            a1.z += (float)h00[6]; a1.w += (float)h00[7];
            a2.x += (float)h01[0]; a2.y += (float)h01[1];
            a2.z += (float)h01[2]; a2.w += (float)h01[3];
            a3.x += (float)h01[4]; a3.y += (float)h01[5];
            a3.z += (float)h01[6]; a3.w += (float)h01[7];
        }
        if (v1) {
            a0.x += (float)h10[0]; a0.y += (float)h10[1];
            a0.z += (float)h10[2]; a0.w += (float)h10[3];
            a1.x += (float)h10[4]; a1.y += (float)h10[5];
            a1.z += (float)h10[6]; a1.w += (float)h10[7];
            a2.x += (float)h11[0]; a2.y += (float)h11[1];
            a2.z += (float)h11[2]; a2.w += (float)h11[3];
            a3.x += (float)h11[4]; a3.y += (float)h11[5];
            a3.z += (float)h11[6]; a3.w += (float)h11[7];
        }
    }
    #pragma unroll
    for (int m = 8; m <= 32; m <<= 1) {
        a0.x += __shfl_xor(a0.x, m); a0.y += __shfl_xor(a0.y, m);
        a0.z += __shfl_xor(a0.z, m); a0.w += __shfl_xor(a0.w, m);
        a1.x += __shfl_xor(a1.x, m); a1.y += __shfl_xor(a1.y, m);
        a1.z += __shfl_xor(a1.z, m); a1.w += __shfl_xor(a1.w, m);
        a2.x += __shfl_xor(a2.x, m); a2.y += __shfl_xor(a2.y, m);
        a2.z += __shfl_xor(a2.z, m); a2.w += __shfl_xor(a2.w, m);
        a3.x += __shfl_xor(a3.x, m); a3.y += __shfl_xor(a3.y, m);
        a3.z += __shfl_xor(a3.z, m); a3.w += __shfl_xor(a3.w, m);
    }

    if (g == 0) {
        float4 b0 = ((const float4*)bias)[q * 2];
        float4 b1 = ((const float4*)bias)[q * 2 + 1];
        float4 b2 = ((const float4*)bias)[16 + q * 2];
        float4 b3 = ((const float4*)bias)[16 + q * 2 + 1];
        half8 o0, o1;
        o0[0] = (_Float16)fmaxf(fmaf(dn, a0.x + (float)sA[0], b0.x), 0.f);
        o0[1] = (_Float16)fmaxf(fmaf(dn, a0.y + (float)sA[1], b0.y), 0.f);
        o0[2] = (_Float16)fmaxf(fmaf(dn, a0.z + (float)sA[2], b0.z), 0.f);
        o0[3] = (_Float16)fmaxf(fmaf(dn, a0.w + (float)sA[3], b0.w), 0.f);
        o0[4] = (_Float16)fmaxf(fmaf(dn, a1.x + (float)sA[4], b1.x), 0.f);
        o0[5] = (_Float16)fmaxf(fmaf(dn, a1.y + (float)sA[5], b1.y), 0.f);
        o0[6] = (_Float16)fmaxf(fmaf(dn, a1.z + (float)sA[6], b1.z), 0.f);
        o0[7] = (_Float16)fmaxf(fmaf(dn, a1.w + (float)sA[7], b1.w), 0.f);
        o1[0] = (_Float16)fmaxf(fmaf(dn, a2.x + (float)sB[0], b2.x), 0.f);
        o1[1] = (_Float16)fmaxf(fmaf(dn, a2.y + (float)sB[1], b2.y), 0.f);
        o1[2] = (_Float16)fmaxf(fmaf(dn, a2.z + (float)sB[2], b2.z), 0.f);
        o1[3] = (_Float16)fmaxf(fmaf(dn, a2.w + (float)sB[3], b2.w), 0.f);
        o1[4] = (_Float16)fmaxf(fmaf(dn, a3.x + (float)sB[4], b3.x), 0.f);
        o1[5] = (_Float16)fmaxf(fmaf(dn, a3.y + (float)sB[5], b3.y), 0.f);
        o1[6] = (_Float16)fmaxf(fmaf(dn, a3.z + (float)sB[6], b3.z), 0.f);
        o1[7] = (_Float16)fmaxf(fmaf(dn, a3.w + (float)sB[7], b3.w), 0.f);
        half8* Hp = (half8*)H16 + (size_t)w * 16 + q;
        Hp[0] = o0;
        Hp[8] = o1;
    }
}

// layer-3 head: same structure; epilogue dots relu row with permuted lin_w
__global__ __launch_bounds__(256) void agg_head_kernel(const int* __restrict__ rowptr,
                                                       const int* __restrict__ edges,
                                                       const float* __restrict__ dinv,
                                                       const _Float16* __restrict__ A16,
                                                       const float* __restrict__ bias,
                                                       const float* __restrict__ lin_w,
                                                       float* __restrict__ nodeval, int N) {
    int w = (blockIdx.x * 256 + threadIdx.x) >> 6;
    if (w >= N) return;
    const int lane = threadIdx.x & 63;
    const int g = lane >> 3;
    const int q = lane & 7;
    const int beg = (w > 0) ? rowptr[w - 1] : 0;
    const int end = rowptr[w];
    const float dn = dinv[w];
    const half8* A8 = (const half8*)A16;

    int myid = (beg + lane < end) ? edges[beg + lane] : 0;
    half8 sA = (half8)(_Float16)0, sB = (half8)(_Float16)0;
    if (g == 0) {
        sA = A8[(size_t)w * 16 + q];
        sB = A8[(size_t)w * 16 + 8 + q];
    }

    float4 a0 = make_float4(0.f, 0.f, 0.f, 0.f);
    float4 a1 = make_float4(0.f, 0.f, 0.f, 0.f);
    float4 a2 = make_float4(0.f, 0.f, 0.f, 0.f);
    float4 a3 = make_float4(0.f, 0.f, 0.f, 0.f);
    for (int base = beg; base < end; base += 16) {
        const int r0 = base - beg + g;
        const int r1 = r0 + 8;
        const int e0 = base + g;
        const int e1 = e0 + 8;
        const bool v0 = e0 < end;
        const bool v1 = e1 < end;
        int s0 = __shfl(myid, r0 < 64 ? r0 : 63);
        int s1 = __shfl(myid, r1 < 64 ? r1 : 63);
        if (r0 >= 64 && v0) s0 = edges[e0];
        if (r1 >= 64 && v1) s1 = edges[e1];
        half8 h00, h01, h10, h11;
        if (v0) {
            const half8* R = A8 + (size_t)s0 * 16 + q;
            h00 = R[0]; h01 = R[8];
        }
        if (v1) {
            const half8* R = A8 + (size_t)s1 * 16 + q;
            h10 = R[0]; h11 = R[8];
        }
        if (v0) {
            a0.x += (float)h00[0]; a0.y += (float)h00[1];
            a0.z += (float)h00[2]; a0.w += (float)h00[3];
            a1.x += (float)h00[4]; a1.y += (float)h00[5];
            a1.z += (float)h00[6]; a1.w += (float)h00[7];
            a2.x += (float)h01[0]; a2.y += (float)h01[1];
            a2.z += (float)h01[2]; a2.w += (float)h01[3];
            a3.x += (float)h01[4]; a3.y += (float)h01[5];
            a3.z += (float)h01[6]; a3.w += (float)h01[7];
        }
        if (v1) {
            a0.x += (float)h10[0]; a0.y += (float)h10[1];
            a0.z += (float)h10[2]; a0.w += (float)h10[3];
            a1.x += (float)h10[4]; a1.y += (float)h10[5];
            a1.z += (float)h10[6]; a1.w += (float)h10[7];
            a2.x += (float)h11[0]; a2.y += (float)h11[1];
            a2.z += (float)h11[2]; a2.w += (float)h11[3];
            a3.x += (float)h11[4]; a3.y += (float)h11[5];
            a3.z += (float)h11[6]; a3.w += (float)h11[7];
        }
    }
    #pragma unroll
    for (int m = 8; m <= 32; m <<= 1) {
        a0.x += __shfl_xor(a0.x, m); a0.y += __shfl_xor(a0.y, m);
        a0.z += __shfl_xor(a0.z, m); a0.w += __shfl_xor(a0.w, m);
        a1.x += __shfl_xor(a1.x, m); a1.y += __shfl_xor(a1.y, m);
        a1.z += __shfl_xor(a1.z, m); a1.w += __shfl_xor(a1.w, m);
        a2.x += __shfl_xor(a2.x, m); a2.y += __shfl_xor(a2.y, m);
        a2.z += __shfl_xor(a2.z, m); a2.w += __shfl_xor(a2.w, m);
        a3.x += __shfl_xor(a3.x, m); a3.y += __shfl_xor(a3.y, m);
        a3.z += __shfl_xor(a3.z, m); a3.w += __shfl_xor(a3.w, m);
    }

    if (g == 0) {
        float4 b0 = ((const float4*)bias)[q * 2];
        float4 b1 = ((const float4*)bias)[q * 2 + 1];
        float4 b2 = ((const float4*)bias)[16 + q * 2];
        float4 b3 = ((const float4*)bias)[16 + q * 2 + 1];
        a0.x = fmaf(dn, a0.x + (float)sA[0], b0.x);
        a0.y = fmaf(dn, a0.y + (float)sA[1], b0.y);
        a0.z = fmaf(dn, a0.z + (float)sA[2], b0.z);
        a0.w = fmaf(dn, a0.w + (float)sA[3], b0.w);
        a1.x = fmaf(dn, a1.x + (float)sA[4], b1.x);
        a1.y = fmaf(dn, a1.y + (float)sA[5], b1.y);
        a1.z = fmaf(dn, a1.z + (float)sA[6], b1.z);
        a1.w = fmaf(dn, a1.w + (float)sA[7], b1.w);
        a2.x = fmaf(dn, a2.x + (float)sB[0], b2.x);
        a2.y = fmaf(dn, a2.y + (float)sB[1], b2.y);
        a2.z = fmaf(dn, a2.z + (float)sB[2], b2.z);
        a2.w = fmaf(dn, a2.w + (float)sB[3], b2.w);
        a3.x = fmaf(dn, a3.x + (float)sB[4], b3.x);
        a3.y = fmaf(dn, a3.y + (float)sB[5], b3.y);
        a3.z = fmaf(dn, a3.z + (float)sB[6], b3.z);
        a3.w = fmaf(dn, a3.w + (float)sB[7], b3.w);
        float4 w0 = ((const float4*)lin_w)[q * 2];
        float4 w1 = ((const float4*)lin_w)[q * 2 + 1];
        float4 w2 = ((const float4*)lin_w)[16 + q * 2];
        float4 w3 = ((const float4*)lin_w)[16 + q * 2 + 1];
        float s = fmaxf(a0.x, 0.f) * w0.x + fmaxf(a0.y, 0.f) * w0.y
                + fmaxf(a0.z, 0.f) * w0.z + fmaxf(a0.w, 0.f) * w0.w
                + fmaxf(a1.x, 0.f) * w1.x + fmaxf(a1.y, 0.f) * w1.y
                + fmaxf(a1.z, 0.f) * w1.z + fmaxf(a1.w, 0.f) * w1.w
                + fmaxf(a2.x, 0.f) * w2.x + fmaxf(a2.y, 0.f) * w2.y
                + fmaxf(a2.z, 0.f) * w2.z + fmaxf(a2.w, 0.f) * w2.w
                + fmaxf(a3.x, 0.f) * w3.x + fmaxf(a3.y, 0.f) * w3.y
                + fmaxf(a3.z, 0.f) * w3.z + fmaxf(a3.w, 0.f) * w3.w;
        s += __shfl_xor(s, 1);
        s += __shfl_xor(s, 2);
        s += __shfl_xor(s, 4);
        if (q == 0) nodeval[w] = s;
    }
}

__device__ __forceinline__ int lower_bound_dev(const int* __restrict__ a, int n, int key) {
    int lo = 0, hi = n;
    while (lo < hi) {
        int mid = (lo + hi) >> 1;
        if (a[mid] < key) lo = mid + 1; else hi = mid;
    }
    return lo;
}

// one block per graph: out[g] = mean(nodeval[lo:hi]) + lin_b  (batch is sorted)
__global__ __launch_bounds__(256) void segreduce_kernel(const float* __restrict__ nodeval,
                                                        const int* __restrict__ batch,
                                                        const float* __restrict__ lin_b,
                                                        float* __restrict__ out, int N) {
    const int g = blockIdx.x;
    const int lo = lower_bound_dev(batch, N, g);
    const int hi = lower_bound_dev(batch, N, g + 1);
    float acc = 0.f;
    for (int n = lo + threadIdx.x; n < hi; n += 256) acc += nodeval[n];
    __shared__ float red[256];
    red[threadIdx.x] = acc;
    __syncthreads();
    for (int s = 128; s > 0; s >>= 1) {
        if (threadIdx.x < s) red[threadIdx.x] += red[threadIdx.x + s];
        __syncthreads();
    }
    if (threadIdx.x == 0) {
        float cnt = (float)(hi - lo);
        out[g] = red[0] / fmaxf(cnt, 1.0f) + lin_b[0];
    }
}

extern "C" void kernel_launch(void* const* d_in, const int* in_sizes, int n_in,
                              void* d_out, int out_size, void* d_ws, size_t ws_size,
                              hipStream_t stream) {
    const float* x     = (const float*)d_in[0];
    const int*   ei    = (const int*)d_in[1];    // [2,E]: rows then cols
    const int*   batch = (const int*)d_in[2];
    const float* W1    = (const float*)d_in[3];
    const float* b1    = (const float*)d_in[4];
    const float* W2    = (const float*)d_in[5];
    const float* b2    = (const float*)d_in[6];
    const float* W3    = (const float*)d_in[7];
    const float* b3    = (const float*)d_in[8];
    const float* lin_w = (const float*)d_in[9];
    const float* lin_b = (const float*)d_in[10];
    float* out = (float*)d_out;

    const int N = in_sizes[0] / 128;
    const int E = in_sizes[1] / 2;
    const int nBlk = (N + 1023) / 1024;
    const int partSize = (N + 7) / 8;            // XCD destination partition
    const int eChunks = (E + 2047) / 2048;       // 8 edges/thread scans
    const int gBlocks = (N + 63) / 64;
    const int aBlocks = ((size_t)N * 64 + 255) / 256;

    // workspace: A16 | H16 | deg | dinv | rowptr | edges(int) | scan | nodeval
    //            | W16 | bperm (3x128 + 128 permuted fp32 bias/lin_w)
    _Float16* A16    = (_Float16*)d_ws;
    _Float16* H16    = A16 + (size_t)N * 128;
    int*   deg       = (int*)(H16 + (size_t)N * 128);
    float* dinv      = (float*)(deg + N);
    int*   rowptr    = (int*)(dinv + N);
    int*   edges     = rowptr + N;
    int*   blockSums = edges + (((size_t)E + 3) & ~(size_t)3);  // keep 16B alignment
    int*   blockOffs = blockSums + 256;
    float* nodeval   = (float*)(blockOffs + 256);
    _Float16* W16    = (_Float16*)(nodeval + N);   // 3 x 16384 fp16 fragments
    float* bperm     = (float*)(W16 + 3 * 16384);  // [b1' b2' b3' lin_w'] x 128

    // ---- CSR build + layer-1 GEMM (overlapped) ----
    hipMemsetAsync(deg, 0, (size_t)N * sizeof(int), stream);
    prep_kernel<<<200 + 8 * eChunks, 256, 0, stream>>>(W1, W2, W3, b1, b2, b3, lin_w,
                                                       W16, bperm, ei + E, deg, E, partSize);
    scan1_kernel<<<nBlk, 256, 0, stream>>>(deg, rowptr, dinv, blockSums, N);
    scan2_kernel<<<1, 128, 0, stream>>>(blockSums, blockOffs, nBlk);
    scan3_kernel<<<(N + 255) / 256, 256, 0, stream>>>(rowptr, blockOffs, N);
    fill_gemm1_kernel<<<gBlocks + 8 * eChunks, 256, 0, stream>>>(
        x, W16, dinv, A16, N, gBlocks, ei, rowptr, edges, E, partSize);

    // layer 1 agg -> H16 (relu fp16)
    agg_kernel<<<aBlocks, 256, 0, stream>>>(rowptr, edges, dinv, A16, bperm, H16, N);
    // layer 2: H16 @ W2 -> A16' ; agg -> H16
    gemm_f16_kernel<<<gBlocks, 256, 0, stream>>>(H16, W16 + 16384, dinv, A16, N);
    agg_kernel<<<aBlocks, 256, 0, stream>>>(rowptr, edges, dinv, A16, bperm + 128, H16, N);
    // layer 3: H16 @ W3 -> A16' ; head agg + dot -> nodeval
    gemm_f16_kernel<<<gBlocks, 256, 0, stream>>>(H16, W16 + 32768, dinv, A16, N);
    agg_head_kernel<<<aBlocks, 256, 0, stream>>>(rowptr, edges, dinv,
                                                 A16, bperm + 256, bperm + 384, nodeval, N);
    segreduce_kernel<<<64, 256, 0, stream>>>(nodeval, batch, lin_b, out, N);
}

// Round 5
// 484.687 us; speedup vs baseline: 1.0758x; 1.0758x over previous
//
#include <hip/hip_runtime.h>

// ---------------------------------------------------------------------------
// GCN forward (R17: two-pass binned CSR build — no random 4B scatter):
//   prep:   [wcast | bias-permute | count_deg (unpartitioned, 1x read)] 
//   scans:  scan1(+dinv) -> scan2 -> scan3(+bucketCursor init, rowptr[N]=E)
//   passA:  [bin edges into 196 coarse buckets (dense run writes) | gemm1]
//   passB:  binfill — 1 block/bucket, LDS cursors from read-only rowptr,
//           node's slots written by ONE block => full write-combining.
//   rowptr is N+1 exclusive starts, never modified after scan3.
//   A16/H16 permuted feature layout f=t*16+m -> m*8+t (R16); W2/W3 fragments
//   use K-row sigma(k)=(k&7)*16+(k>>3); bias/lin_w permuted copies.
//   agg: 8 lanes/edge full-line gathers, coop edge-id prefetch (R15).
// ---------------------------------------------------------------------------

typedef __attribute__((ext_vector_type(4))) float f32x4;
typedef __attribute__((ext_vector_type(8))) _Float16 half8;

// ---- gemm1 body: A16' = fp16(dinv[r] * (x @ W1)), permuted store ----------

__device__ __forceinline__ void gemm_f32_body(const float* __restrict__ H,
                                              const _Float16* __restrict__ W16,
                                              const float* __restrict__ dinv,
                                              _Float16* __restrict__ T16,
                                              int N, int bid) {
    const int tid = threadIdx.x;
    const int wv = tid >> 6;
    const int lane = tid & 63;
    const int r0 = bid * 64 + wv * 16;
    const int mrow = lane & 15;
    const int kq = lane >> 4;
    const int grow = r0 + mrow;
    const bool rok = grow < N;

    f32x4 acc[8];
    #pragma unroll
    for (int t = 0; t < 8; ++t) acc[t] = (f32x4){0.f, 0.f, 0.f, 0.f};

    #pragma unroll
    for (int c = 0; c < 4; ++c) {
        half8 a = (half8)(_Float16)0;
        if (rok) {
            const f32x4* Hp = (const f32x4*)(H + (size_t)grow * 128 + c * 32 + kq * 8);
            f32x4 a0 = __builtin_nontemporal_load(Hp);
            f32x4 a1 = __builtin_nontemporal_load(Hp + 1);
            a[0] = (_Float16)a0[0]; a[1] = (_Float16)a0[1];
            a[2] = (_Float16)a0[2]; a[3] = (_Float16)a0[3];
            a[4] = (_Float16)a1[0]; a[5] = (_Float16)a1[1];
            a[6] = (_Float16)a1[2]; a[7] = (_Float16)a1[3];
        }
        #pragma unroll
        for (int t = 0; t < 8; ++t) {
            half8 w = *(const half8*)&W16[(((c * 8 + t) * 64) + lane) * 8];
            acc[t] = __builtin_amdgcn_mfma_f32_16x16x32_f16(a, w, acc[t], 0, 0, 0);
        }
    }
    #pragma unroll
    for (int r = 0; r < 4; ++r) {
        int orow = r0 + kq * 4 + r;
        if (orow < N) {
            float dv = dinv[orow];
            half8 o;
            #pragma unroll
            for (int t = 0; t < 8; ++t) o[t] = (_Float16)(acc[t][r] * dv);
            *(half8*)(T16 + (size_t)orow * 128 + mrow * 8) = o;
        }
    }
}

// ---- merged launch 1: wcast (192) | bias-permute (192..199) | count_deg ---
__global__ __launch_bounds__(256) void prep_kernel(const float* __restrict__ W1,
                                                   const float* __restrict__ W2,
                                                   const float* __restrict__ W3,
                                                   const float* __restrict__ b1,
                                                   const float* __restrict__ b2,
                                                   const float* __restrict__ b3,
                                                   const float* __restrict__ lin_w,
                                                   _Float16* __restrict__ W16,
                                                   float* __restrict__ bperm,
                                                   const int* __restrict__ col,
                                                   int* __restrict__ deg,
                                                   int E) {
    if (blockIdx.x < 192) {
        int layer = blockIdx.x >> 6;
        const float* W = (layer == 0) ? W1 : (layer == 1) ? W2 : W3;
        _Float16* Wd = W16 + layer * 16384;
        int i = (blockIdx.x & 63) * 256 + threadIdx.x;
        int j = i & 7;
        int l = (i >> 3) & 63;
        int t = (i >> 9) & 7;
        int c = i >> 12;
        int k = c * 32 + (l >> 4) * 8 + j;
        int ksrc = (layer == 0) ? k : ((k & 7) * 16 + (k >> 3));
        int n = t * 16 + (l & 15);
        Wd[i] = (_Float16)W[ksrc * 128 + n];
    } else if (blockIdx.x < 200) {
        int a = blockIdx.x - 192;
        if (a < 4 && threadIdx.x < 128) {
            const float* src = (a == 0) ? b1 : (a == 1) ? b2 : (a == 2) ? b3 : lin_w;
            int p2 = threadIdx.x;
            bperm[a * 128 + p2] = src[(p2 & 7) * 16 + (p2 >> 3)];
        }
    } else {
        // unpartitioned degree count: each edge read ONCE (was 8x XCD-replicated)
        int bid = blockIdx.x - 200;
        const int e0 = bid * 2048 + threadIdx.x * 8;
        if (e0 >= E) return;
        if (((E & 3) == 0) && e0 + 7 < E) {
            int4 cA = *(const int4*)&col[e0];
            int4 cB = *(const int4*)&col[e0 + 4];
            atomicAdd(&deg[cA.x], 1); atomicAdd(&deg[cA.y], 1);
            atomicAdd(&deg[cA.z], 1); atomicAdd(&deg[cA.w], 1);
            atomicAdd(&deg[cB.x], 1); atomicAdd(&deg[cB.y], 1);
            atomicAdd(&deg[cB.z], 1); atomicAdd(&deg[cB.w], 1);
        } else {
            for (int j2 = 0; j2 < 8; ++j2) {
                int e = e0 + j2;
                if (e < E) atomicAdd(&deg[col[e]], 1);
            }
        }
    }
}

// per-block exclusive scan of deg (1024/block) -> rowptr starts; dinv = rsqrt(deg+1)
__global__ __launch_bounds__(256) void scan1_kernel(const int* __restrict__ deg,
                                                    int* __restrict__ rowptr,
                                                    float* __restrict__ dinv,
                                                    int* __restrict__ blockSums, int N) {
    __shared__ int ts[256];
    const int t = threadIdx.x;
    const int base = blockIdx.x * 1024 + t * 4;
    int v0 = 0, v1 = 0, v2 = 0, v3 = 0;
    if (base + 3 < N) {
        int4 v = *(const int4*)&deg[base];
        v0 = v.x; v1 = v.y; v2 = v.z; v3 = v.w;
    } else {
        if (base + 0 < N) v0 = deg[base + 0];
        if (base + 1 < N) v1 = deg[base + 1];
        if (base + 2 < N) v2 = deg[base + 2];
        if (base + 3 < N) v3 = deg[base + 3];
    }
    if (base + 0 < N) dinv[base + 0] = 1.0f / sqrtf((float)v0 + 1.0f);
    if (base + 1 < N) dinv[base + 1] = 1.0f / sqrtf((float)v1 + 1.0f);
    if (base + 2 < N) dinv[base + 2] = 1.0f / sqrtf((float)v2 + 1.0f);
    if (base + 3 < N) dinv[base + 3] = 1.0f / sqrtf((float)v3 + 1.0f);
    const int tot = v0 + v1 + v2 + v3;
    ts[t] = tot;
    __syncthreads();
    for (int off = 1; off < 256; off <<= 1) {
        int add = (t >= off) ? ts[t - off] : 0;
        __syncthreads();
        ts[t] += add;
        __syncthreads();
    }
    const int excl = ts[t] - tot;
    if (base + 0 < N) rowptr[base + 0] = excl;
    if (base + 1 < N) rowptr[base + 1] = excl + v0;
    if (base + 2 < N) rowptr[base + 2] = excl + v0 + v1;
    if (base + 3 < N) rowptr[base + 3] = excl + v0 + v1 + v2;
    if (t == 255) blockSums[blockIdx.x] = ts[255];
}

__global__ __launch_bounds__(128) void scan2_kernel(const int* __restrict__ blockSums,
                                                    int* __restrict__ blockOffs, int B) {
    __shared__ int ts[128];
    const int t = threadIdx.x;
    ts[t] = (t < B) ? blockSums[t] : 0;
    __syncthreads();
    for (int off = 1; off < 128; off <<= 1) {
        int add = (t >= off) ? ts[t - off] : 0;
        __syncthreads();
        ts[t] += add;
        __syncthreads();
    }
    if (t < B) blockOffs[t] = ts[t];
}

// finalize rowptr; init per-bucket cursors; rowptr[N] = E
__global__ __launch_bounds__(256) void scan3_kernel(int* __restrict__ rowptr,
                                                    const int* __restrict__ blockOffs,
                                                    int* __restrict__ bucketCursor,
                                                    int N, int E) {
    int i = blockIdx.x * 256 + threadIdx.x;
    if (i == 0) rowptr[N] = E;
    if (i >= N) return;
    int b = i >> 10;
    int v = rowptr[i];
    if (b > 0) v += blockOffs[b - 1];
    rowptr[i] = v;
    if ((i & 511) == 0) bucketCursor[i >> 9] = v;   // bucket start
}

// ---- merged launch 2: passA coarse binning (fBlocks) | gemm1 (rest) -------
// passA: 2048 edges/block in regs; LDS hist -> ONE global atomic per
// (bucket,block) reserving a contiguous run -> dense run writes (combine).
// coarse entry packs (dst&511)<<23 | src  (needs N < 2^23).
__global__ __launch_bounds__(256) void fill_gemm1_kernel(
        const float* __restrict__ x, const _Float16* __restrict__ W16,
        const float* __restrict__ dinv, _Float16* __restrict__ A16,
        int N, int fBlocks, const int* __restrict__ ei,
        int* __restrict__ bucketCursor, int* __restrict__ coarse, int E) {
    __shared__ int hist[256];
    __shared__ int base_s[256];
    __shared__ int lcur[256];
    if ((int)blockIdx.x < fBlocks) {
        const int tid = threadIdx.x;
        const int nb = (N + 511) >> 9;           // <= 256 assumed (N <= 131072)
        for (int i = tid; i < nb; i += 256) { hist[i] = 0; lcur[i] = 0; }
        __syncthreads();
        const int e0 = blockIdx.x * 2048 + tid * 8;
        int c[8], r[8];
        if (e0 < E && ((E & 3) == 0) && e0 + 7 < E) {
            int4 cA = *(const int4*)&ei[E + e0];
            int4 cB = *(const int4*)&ei[E + e0 + 4];
            int4 rA = *(const int4*)&ei[e0];
            int4 rB = *(const int4*)&ei[e0 + 4];
            c[0] = cA.x; c[1] = cA.y; c[2] = cA.z; c[3] = cA.w;
            c[4] = cB.x; c[5] = cB.y; c[6] = cB.z; c[7] = cB.w;
            r[0] = rA.x; r[1] = rA.y; r[2] = rA.z; r[3] = rA.w;
            r[4] = rB.x; r[5] = rB.y; r[6] = rB.z; r[7] = rB.w;
        } else {
            #pragma unroll
            for (int j = 0; j < 8; ++j) {
                int e = e0 + j;
                c[j] = (e < E) ? ei[E + e] : -1;
                r[j] = (e < E) ? ei[e] : 0;
            }
        }
        #pragma unroll
        for (int j = 0; j < 8; ++j)
            if (c[j] >= 0) atomicAdd(&hist[c[j] >> 9], 1);
        __syncthreads();
        for (int i = tid; i < nb; i += 256) {
            int h = hist[i];
            base_s[i] = h ? atomicAdd(&bucketCursor[i], h) : 0;
        }
        __syncthreads();
        #pragma unroll
        for (int j = 0; j < 8; ++j) {
            if (c[j] >= 0) {
                int b = c[j] >> 9;
                int idx = atomicAdd(&lcur[b], 1);
                coarse[base_s[b] + idx] =
                    (int)(((unsigned)(c[j] & 511) << 23) | (unsigned)r[j]);
            }
        }
    } else {
        gemm_f32_body(x, W16, dinv, A16, N, (int)blockIdx.x - fBlocks);
    }
}

// ---- passB: one block per bucket; LDS cursors from read-only rowptr -------
// A node's slots are written densely by ONE block on ONE XCD => full-line
// write-combining. No global rowptr atomics.
__global__ __launch_bounds__(512) void binfill_kernel(const int* __restrict__ rowptr,
                                                      const int* __restrict__ bucketEnd,
                                                      const int* __restrict__ coarse,
                                                      int* __restrict__ edges, int N) {
    const int b = blockIdx.x;
    const int base_node = b << 9;
    __shared__ int cur[512];
    const int nNodes = min(512, N - base_node);
    for (int i = threadIdx.x; i < nNodes; i += 512) cur[i] = rowptr[base_node + i];
    __syncthreads();
    const int start = rowptr[base_node];
    const int end = bucketEnd[b];                 // bucketCursor after passA
    for (int e = start + threadIdx.x; e < end; e += 512) {
        int pk = coarse[e];
        int dlow = (int)(((unsigned)pk) >> 23);
        int src = pk & ((1 << 23) - 1);
        int slot = atomicAdd(&cur[dlow], 1);
        edges[slot] = src;
    }
}

// A16' = fp16( dinv[row] * (H16 @ W16) ), permuted store (layers 2/3)
__global__ __launch_bounds__(256) void gemm_f16_kernel(const _Float16* __restrict__ H16,
                                                       const _Float16* __restrict__ W16,
                                                       const float* __restrict__ dinv,
                                                       _Float16* __restrict__ T16,
                                                       int N) {
    const int tid = threadIdx.x;
    const int wv = tid >> 6;
    const int lane = tid & 63;
    const int r0 = blockIdx.x * 64 + wv * 16;
    const int mrow = lane & 15;
    const int kq = lane >> 4;
    const int grow = r0 + mrow;
    const bool rok = grow < N;

    f32x4 acc[8];
    #pragma unroll
    for (int t = 0; t < 8; ++t) acc[t] = (f32x4){0.f, 0.f, 0.f, 0.f};

    #pragma unroll
    for (int c = 0; c < 4; ++c) {
        half8 a = (half8)(_Float16)0;
        if (rok) a = *(const half8*)(H16 + (size_t)grow * 128 + c * 32 + kq * 8);
        #pragma unroll
        for (int t = 0; t < 8; ++t) {
            half8 w = *(const half8*)&W16[(((c * 8 + t) * 64) + lane) * 8];
            acc[t] = __builtin_amdgcn_mfma_f32_16x16x32_f16(a, w, acc[t], 0, 0, 0);
        }
    }
    #pragma unroll
    for (int r = 0; r < 4; ++r) {
        int orow = r0 + kq * 4 + r;
        if (orow < N) {
            float dv = dinv[orow];
            half8 o;
            #pragma unroll
            for (int t = 0; t < 8; ++t) o[t] = (_Float16)(acc[t][r] * dv);
            *(half8*)(T16 + (size_t)orow * 128 + mrow * 8) = o;
        }
    }
}

// one wave per node; 8 lanes/edge; lane covers chunks (q, 8+q); coop edge-id
// prefetch; 2-edge unroll. rowptr is N+1 starts: bucket w = [rowptr[w], rowptr[w+1])
__global__ __launch_bounds__(256) void agg_kernel(const int* __restrict__ rowptr,
                                                  const int* __restrict__ edges,
                                                  const float* __restrict__ dinv,
                                                  const _Float16* __restrict__ A16,
                                                  const float* __restrict__ bias,
                                                  _Float16* __restrict__ H16, int N) {
    int w = (blockIdx.x * 256 + threadIdx.x) >> 6;
    if (w >= N) return;
    const int lane = threadIdx.x & 63;
    const int g = lane >> 3;
    const int q = lane & 7;
    const int beg = rowptr[w];
    const int end = rowptr[w + 1];
    const float dn = dinv[w];
    const half8* A8 = (const half8*)A16;

    int myid = (beg + lane < end) ? edges[beg + lane] : 0;
    half8 sA = (half8)(_Float16)0, sB = (half8)(_Float16)0;
    if (g == 0) {
        sA = A8[(size_t)w * 16 + q];
        sB = A8[(size_t)w * 16 + 8 + q];
    }

    float4 a0 = make_float4(0.f, 0.f, 0.f, 0.f);
    float4 a1 = make_float4(0.f, 0.f, 0.f, 0.f);
    float4 a2 = make_float4(0.f, 0.f, 0.f, 0.f);
    float4 a3 = make_float4(0.f, 0.f, 0.f, 0.f);
    for (int base = beg; base < end; base += 16) {
        const int r0 = base - beg + g;
        const int r1 = r0 + 8;
        const int e0 = base + g;
        const int e1 = e0 + 8;
        const bool v0 = e0 < end;
        const bool v1 = e1 < end;
        int s0 = __shfl(myid, r0 < 64 ? r0 : 63);
        int s1 = __shfl(myid, r1 < 64 ? r1 : 63);
        if (r0 >= 64 && v0) s0 = edges[e0];
        if (r1 >= 64 && v1) s1 = edges[e1];
        half8 h00, h01, h10, h11;
        if (v0) {
            const half8* R = A8 + (size_t)s0 * 16 + q;
            h00 = R[0]; h01 = R[8];
        }
        if (v1) {
            const half8* R = A8 + (size_t)s1 * 16 + q;
            h10 = R[0]; h11 = R[8];
        }
        if (v0) {
            a0.x += (float)h00[0]; a0.y += (float)h00[1];
            a0.z += (float)h00[2]; a0.w += (float)h00[3];
            a1.x += (float)h00[4]; a1.y += (float)h00[5];
            a1.z += (float)h00[6]; a1.w += (float)h00[7];
            a2.x += (float)h01[0]; a2.y += (float)h01[1];
            a2.z += (float)h01[2]; a2.w += (float)h01[3];
            a3.x += (float)h01[4]; a3.y += (float)h01[5];
            a3.z += (float)h01[6]; a3.w += (float)h01[7];
        }
        if (v1) {
            a0.x += (float)h10[0]; a0.y += (float)h10[1];
            a0.z += (float)h10[2]; a0.w += (float)h10[3];
            a1.x += (float)h10[4]; a1.y += (float)h10[5];
            a1.z += (float)h10[6]; a1.w += (float)h10[7];
            a2.x += (float)h11[0]; a2.y += (float)h11[1];
            a2.z += (float)h11[2]; a2.w += (float)h11[3];
            a3.x += (float)h11[4]; a3.y += (float)h11[5];
            a3.z += (float)h11[6]; a3.w += (float)h11[7];
        }
    }
    #pragma unroll
    for (int m = 8; m <= 32; m <<= 1) {
        a0.x += __shfl_xor(a0.x, m); a0.y += __shfl_xor(a0.y, m);
        a0.z += __shfl_xor(a0.z, m); a0.w += __shfl_xor(a0.w, m);
        a1.x += __shfl_xor(a1.x, m); a1.y += __shfl_xor(a1.y, m);
        a1.z += __shfl_xor(a1.z, m); a1.w += __shfl_xor(a1.w, m);
        a2.x += __shfl_xor(a2.x, m); a2.y += __shfl_xor(a2.y, m);
        a2.z += __shfl_xor(a2.z, m); a2.w += __shfl_xor(a2.w, m);
        a3.x += __shfl_xor(a3.x, m); a3.y += __shfl_xor(a3.y, m);
        a3.z += __shfl_xor(a3.z, m); a3.w += __shfl_xor(a3.w, m);
    }

    if (g == 0) {
        float4 b0 = ((const float4*)bias)[q * 2];
        float4 b1 = ((const float4*)bias)[q * 2 + 1];
        float4 b2 = ((const float4*)bias)[16 + q * 2];
        float4 b3 = ((const float4*)bias)[16 + q * 2 + 1];
        half8 o0, o1;
        o0[0] = (_Float16)fmaxf(fmaf(dn, a0.x + (float)sA[0], b0.x), 0.f);
        o0[1] = (_Float16)fmaxf(fmaf(dn, a0.y + (float)sA[1], b0.y), 0.f);
        o0[2] = (_Float16)fmaxf(fmaf(dn, a0.z + (float)sA[2], b0.z), 0.f);
        o0[3] = (_Float16)fmaxf(fmaf(dn, a0.w + (float)sA[3], b0.w), 0.f);
        o0[4] = (_Float16)fmaxf(fmaf(dn, a1.x + (float)sA[4], b1.x), 0.f);
        o0[5] = (_Float16)fmaxf(fmaf(dn, a1.y + (float)sA[5], b1.y), 0.f);
        o0[6] = (_Float16)fmaxf(fmaf(dn, a1.z + (float)sA[6], b1.z), 0.f);
        o0[7] = (_Float16)fmaxf(fmaf(dn, a1.w + (float)sA[7], b1.w), 0.f);
        o1[0] = (_Float16)fmaxf(fmaf(dn, a2.x + (float)sB[0], b2.x), 0.f);
        o1[1] = (_Float16)fmaxf(fmaf(dn, a2.y + (float)sB[1], b2.y), 0.f);
        o1[2] = (_Float16)fmaxf(fmaf(dn, a2.z + (float)sB[2], b2.z), 0.f);
        o1[3] = (_Float16)fmaxf(fmaf(dn, a2.w + (float)sB[3], b2.w), 0.f);
        o1[4] = (_Float16)fmaxf(fmaf(dn, a3.x + (float)sB[4], b3.x), 0.f);
        o1[5] = (_Float16)fmaxf(fmaf(dn, a3.y + (float)sB[5], b3.y), 0.f);
        o1[6] = (_Float16)fmaxf(fmaf(dn, a3.z + (float)sB[6], b3.z), 0.f);
        o1[7] = (_Float16)fmaxf(fmaf(dn, a3.w + (float)sB[7], b3.w), 0.f);
        half8* Hp = (half8*)H16 + (size_t)w * 16 + q;
        Hp[0] = o0;
        Hp[8] = o1;
    }
}

// layer-3 head: same structure; epilogue dots relu row with permuted lin_w
__global__ __launch_bounds__(256) void agg_head_kernel(const int* __restrict__ rowptr,
                                                       const int* __restrict__ edges,
                                                       const float* __restrict__ dinv,
                                                       const _Float16* __restrict__ A16,
                                                       const float* __restrict__ bias,
                                                       const float* __restrict__ lin_w,
                                                       float* __restrict__ nodeval, int N) {
    int w = (blockIdx.x * 256 + threadIdx.x) >> 6;
    if (w >= N) return;
    const int lane = threadIdx.x & 63;
    const int g = lane >> 3;
    const int q = lane & 7;
    const int beg = rowptr[w];
    const int end = rowptr[w + 1];
    const float dn = dinv[w];
    const half8* A8 = (const half8*)A16;

    int myid = (beg + lane < end) ? edges[beg + lane] : 0;
    half8 sA = (half8)(_Float16)0, sB = (half8)(_Float16)0;
    if (g == 0) {
        sA = A8[(size_t)w * 16 + q];
        sB = A8[(size_t)w * 16 + 8 + q];
    }

    float4 a0 = make_float4(0.f, 0.f, 0.f, 0.f);
    float4 a1 = make_float4(0.f, 0.f, 0.f, 0.f);
    float4 a2 = make_float4(0.f, 0.f, 0.f, 0.f);
    float4 a3 = make_float4(0.f, 0.f, 0.f, 0.f);
    for (int base = beg; base < end; base += 16) {
        const int r0 = base - beg + g;
        const int r1 = r0 + 8;
        const int e0 = base + g;
        const int e1 = e0 + 8;
        const bool v0 = e0 < end;
        const bool v1 = e1 < end;
        int s0 = __shfl(myid, r0 < 64 ? r0 : 63);
        int s1 = __shfl(myid, r1 < 64 ? r1 : 63);
        if (r0 >= 64 && v0) s0 = edges[e0];
        if (r1 >= 64 && v1) s1 = edges[e1];
        half8 h00, h01, h10, h11;
        if (v0) {
            const half8* R = A8 + (size_t)s0 * 16 + q;
            h00 = R[0]; h01 = R[8];
        }
        if (v1) {
            const half8* R = A8 + (size_t)s1 * 16 + q;
            h10 = R[0]; h11 = R[8];
        }
        if (v0) {
            a0.x += (float)h00[0]; a0.y += (float)h00[1];
            a0.z += (float)h00[2]; a0.w += (float)h00[3];
            a1.x += (float)h00[4]; a1.y += (float)h00[5];
            a1.z += (float)h00[6]; a1.w += (float)h00[7];
            a2.x += (float)h01[0]; a2.y += (float)h01[1];
            a2.z += (float)h01[2]; a2.w += (float)h01[3];
            a3.x += (float)h01[4]; a3.y += (float)h01[5];
            a3.z += (float)h01[6]; a3.w += (float)h01[7];
        }
        if (v1) {
            a0.x += (float)h10[0]; a0.y += (float)h10[1];
            a0.z += (float)h10[2]; a0.w += (float)h10[3];
            a1.x += (float)h10[4]; a1.y += (float)h10[5];
            a1.z += (float)h10[6]; a1.w += (float)h10[7];
            a2.x += (float)h11[0]; a2.y += (float)h11[1];
            a2.z += (float)h11[2]; a2.w += (float)h11[3];
            a3.x += (float)h11[4]; a3.y += (float)h11[5];
            a3.z += (float)h11[6]; a3.w += (float)h11[7];
        }
    }
    #pragma unroll
    for (int m = 8; m <= 32; m <<= 1) {
        a0.x += __shfl_xor(a0.x, m); a0.y += __shfl_xor(a0.y, m);
        a0.z += __shfl_xor(a0.z, m); a0.w += __shfl_xor(a0.w, m);
        a1.x += __shfl_xor(a1.x, m); a1.y += __shfl_xor(a1.y, m);
        a1.z += __shfl_xor(a1.z, m); a1.w += __shfl_xor(a1.w, m);
        a2.x += __shfl_xor(a2.x, m); a2.y += __shfl_xor(a2.y, m);
        a2.z += __shfl_xor(a2.z, m); a2.w += __shfl_xor(a2.w, m);
        a3.x += __shfl_xor(a3.x, m); a3.y += __shfl_xor(a3.y, m);
        a3.z += __shfl_xor(a3.z, m); a3.w += __shfl_xor(a3.w, m);
    }

    if (g == 0) {
        float4 b0 = ((const float4*)bias)[q * 2];
        float4 b1 = ((const float4*)bias)[q * 2 + 1];
        float4 b2 = ((const float4*)bias)[16 + q * 2];
        float4 b3 = ((const float4*)bias)[16 + q * 2 + 1];
        a0.x = fmaf(dn, a0.x + (float)sA[0], b0.x);
        a0.y = fmaf(dn, a0.y + (float)sA[1], b0.y);
        a0.z = fmaf(dn, a0.z + (float)sA[2], b0.z);
        a0.w = fmaf(dn, a0.w + (float)sA[3], b0.w);
        a1.x = fmaf(dn, a1.x + (float)sA[4], b1.x);
        a1.y = fmaf(dn, a1.y + (float)sA[5], b1.y);
        a1.z = fmaf(dn, a1.z + (float)sA[6], b1.z);
        a1.w = fmaf(dn, a1.w + (float)sA[7], b1.w);
        a2.x = fmaf(dn, a2.x + (float)sB[0], b2.x);
        a2.y = fmaf(dn, a2.y + (float)sB[1], b2.y);
        a2.z = fmaf(dn, a2.z + (float)sB[2], b2.z);
        a2.w = fmaf(dn, a2.w + (float)sB[3], b2.w);
        a3.x = fmaf(dn, a3.x + (float)sB[4], b3.x);
        a3.y = fmaf(dn, a3.y + (float)sB[5], b3.y);
        a3.z = fmaf(dn, a3.z + (float)sB[6], b3.z);
        a3.w = fmaf(dn, a3.w + (float)sB[7], b3.w);
        float4 w0 = ((const float4*)lin_w)[q * 2];
        float4 w1 = ((const float4*)lin_w)[q * 2 + 1];
        float4 w2 = ((const float4*)lin_w)[16 + q * 2];
        float4 w3 = ((const float4*)lin_w)[16 + q * 2 + 1];
        float s = fmaxf(a0.x, 0.f) * w0.x + fmaxf(a0.y, 0.f) * w0.y
                + fmaxf(a0.z, 0.f) * w0.z + fmaxf(a0.w, 0.f) * w0.w
                + fmaxf(a1.x, 0.f) * w1.x + fmaxf(a1.y, 0.f) * w1.y
                + fmaxf(a1.z, 0.f) * w1.z + fmaxf(a1.w, 0.f) * w1.w
                + fmaxf(a2.x, 0.f) * w2.x + fmaxf(a2.y, 0.f) * w2.y
                + fmaxf(a2.z, 0.f) * w2.z + fmaxf(a2.w, 0.f) * w2.w
                + fmaxf(a3.x, 0.f) * w3.x + fmaxf(a3.y, 0.f) * w3.y
                + fmaxf(a3.z, 0.f) * w3.z + fmaxf(a3.w, 0.f) * w3.w;
        s += __shfl_xor(s, 1);
        s += __shfl_xor(s, 2);
        s += __shfl_xor(s, 4);
        if (q == 0) nodeval[w] = s;
    }
}

__device__ __forceinline__ int lower_bound_dev(const int* __restrict__ a, int n, int key) {
    int lo = 0, hi = n;
    while (lo < hi) {
        int mid = (lo + hi) >> 1;
        if (a[mid] < key) lo = mid + 1; else hi = mid;
    }
    return lo;
}

// one block per graph: out[g] = mean(nodeval[lo:hi]) + lin_b  (batch is sorted)
__global__ __launch_bounds__(256) void segreduce_kernel(const float* __restrict__ nodeval,
                                                        const int* __restrict__ batch,
                                                        const float* __restrict__ lin_b,
                                                        float* __restrict__ out, int N) {
    const int g = blockIdx.x;
    const int lo = lower_bound_dev(batch, N, g);
    const int hi = lower_bound_dev(batch, N, g + 1);
    float acc = 0.f;
    for (int n = lo + threadIdx.x; n < hi; n += 256) acc += nodeval[n];
    __shared__ float red[256];
    red[threadIdx.x] = acc;
    __syncthreads();
    for (int s = 128; s > 0; s >>= 1) {
        if (threadIdx.x < s) red[threadIdx.x] += red[threadIdx.x + s];
        __syncthreads();
    }
    if (threadIdx.x == 0) {
        float cnt = (float)(hi - lo);
        out[g] = red[0] / fmaxf(cnt, 1.0f) + lin_b[0];
    }
}

extern "C" void kernel_launch(void* const* d_in, const int* in_sizes, int n_in,
                              void* d_out, int out_size, void* d_ws, size_t ws_size,
                              hipStream_t stream) {
    const float* x     = (const float*)d_in[0];
    const int*   ei    = (const int*)d_in[1];    // [2,E]: rows then cols
    const int*   batch = (const int*)d_in[2];
    const float* W1    = (const float*)d_in[3];
    const float* b1    = (const float*)d_in[4];
    const float* W2    = (const float*)d_in[5];
    const float* b2    = (const float*)d_in[6];
    const float* W3    = (const float*)d_in[7];
    const float* b3    = (const float*)d_in[8];
    const float* lin_w = (const float*)d_in[9];
    const float* lin_b = (const float*)d_in[10];
    float* out = (float*)d_out;

    const int N = in_sizes[0] / 128;
    const int E = in_sizes[1] / 2;
    const int nBlk = (N + 1023) / 1024;
    const int nb = (N + 511) >> 9;               // coarse buckets (512 nodes each)
    const int fBlocks = (E + 2047) / 2048;       // 8 edges/thread passes
    const int gBlocks = (N + 63) / 64;
    const int aBlocks = ((size_t)N * 64 + 255) / 256;

    // workspace: A16 | H16 | deg | dinv | rowptr[N+1+pad] | edges | coarse
    //            | bucketCursor | blockSums | blockOffs | nodeval | W16 | bperm
    _Float16* A16    = (_Float16*)d_ws;
    _Float16* H16    = A16 + (size_t)N * 128;
    int*   deg       = (int*)(H16 + (size_t)N * 128);
    float* dinv      = (float*)(deg + N);
    int*   rowptr    = (int*)(dinv + N);                       // N+1 entries
    int*   edges     = rowptr + (((size_t)N + 4) & ~(size_t)3);
    int*   coarse    = edges + (((size_t)E + 3) & ~(size_t)3);
    int*   bucketCursor = coarse + (((size_t)E + 3) & ~(size_t)3);
    int*   blockSums = bucketCursor + 256;
    int*   blockOffs = blockSums + 256;
    float* nodeval   = (float*)(blockOffs + 256);
    _Float16* W16    = (_Float16*)(nodeval + N);   // 3 x 16384 fp16 fragments
    float* bperm     = (float*)(W16 + 3 * 16384);  // [b1' b2' b3' lin_w'] x 128

    // ---- CSR build (binned) + layer-1 GEMM ----
    hipMemsetAsync(deg, 0, (size_t)N * sizeof(int), stream);
    prep_kernel<<<200 + fBlocks, 256, 0, stream>>>(W1, W2, W3, b1, b2, b3, lin_w,
                                                   W16, bperm, ei + E, deg, E);
    scan1_kernel<<<nBlk, 256, 0, stream>>>(deg, rowptr, dinv, blockSums, N);
    scan2_kernel<<<1, 128, 0, stream>>>(blockSums, blockOffs, nBlk);
    scan3_kernel<<<(N + 255) / 256, 256, 0, stream>>>(rowptr, blockOffs,
                                                      bucketCursor, N, E);
    // passA coarse binning co-scheduled with gemm1 (dense runs => no write-amp)
    fill_gemm1_kernel<<<fBlocks + gBlocks, 256, 0, stream>>>(
        x, W16, dinv, A16, N, fBlocks, ei, bucketCursor, coarse, E);
    // passB: per-bucket dense CSR fill
    binfill_kernel<<<nb, 512, 0, stream>>>(rowptr, bucketCursor, coarse, edges, N);

    // layer 1 agg -> H16 (relu fp16)
    agg_kernel<<<aBlocks, 256, 0, stream>>>(rowptr, edges, dinv, A16, bperm, H16, N);
    // layer 2: H16 @ W2 -> A16' ; agg -> H16
    gemm_f16_kernel<<<gBlocks, 256, 0, stream>>>(H16, W16 + 16384, dinv, A16, N);
    agg_kernel<<<aBlocks, 256, 0, stream>>>(rowptr, edges, dinv, A16, bperm + 128, H16, N);
    // layer 3: H16 @ W3 -> A16' ; head agg + dot -> nodeval
    gemm_f16_kernel<<<gBlocks, 256, 0, stream>>>(H16, W16 + 32768, dinv, A16, N);
    agg_head_kernel<<<aBlocks, 256, 0, stream>>>(rowptr, edges, dinv,
                                                 A16, bperm + 256, bperm + 384, nodeval, N);
    segreduce_kernel<<<64, 256, 0, stream>>>(nodeval, batch, lin_b, out, N);
}